// Round 13
// baseline (321.284 us; speedup 1.0000x reference)
//
#include <hip/hip_runtime.h>
#include <math.h>

#define BB 2
#define CIN 256
#define COUT 128
#define LL 4096
#define DI 256
#define DS 16

#define SC_T 16     // chunk length
#define SC_NC 256   // chunks per batch
#define SXP 260     // sxc pitch: bank step 4/row -> conflict-free
#define WXP 260     // sWx pitch
#define NSUP 16     // superchunks
#define CPS 16      // chunks per superchunk

#define L2E 1.44269504088896340736f
#define LN2 0.69314718055994530942f

// native transcendentals: v_exp_f32 (2^x), v_log_f32 (log2), v_rcp_f32
__device__ __forceinline__ float ex2_(float x){ return __builtin_amdgcn_exp2f(x); }
__device__ __forceinline__ float fexp_(float x){ return ex2_(x * L2E); }
__device__ __forceinline__ float rcp_(float x){ return __builtin_amdgcn_rcpf(x); }
__device__ __forceinline__ float silu_(float x){ return x * rcp_(1.f + fexp_(-x)); }
__device__ __forceinline__ float sigm_(float x){ return rcp_(1.f + fexp_(-x)); }
__device__ __forceinline__ float softplus_(float x){
  return (x > 20.f) ? x : LN2 * __builtin_amdgcn_logf(1.f + fexp_(x));
}

// ---------- prep: W_eff + all transposes + Aexp (one dispatch) ----------
__global__ __launch_bounds__(256) void k_prep(
    const float* __restrict__ w_up, const float* __restrict__ w_fuse,
    const float* __restrict__ gW_in, const float* __restrict__ gW_gate,
    const float* __restrict__ gW_out, const float* __restrict__ m_Win,
    const float* __restrict__ m_Wout, const float* __restrict__ m_Alog,
    float* __restrict__ W_eff,
    float* __restrict__ gW_inT, float* __restrict__ gW_gateT,
    float* __restrict__ gW_outT, float* __restrict__ m_WinT,
    float* __restrict__ m_WoutT, float* __restrict__ Aexp){
  int bid = blockIdx.x;
  if (bid < 512){
    int idx = bid * 256 + threadIdx.x;   // 4*256*128
    int o = idx & 127;
    int c = (idx >> 7) & 255;
    int p = idx >> 15;
    int kh = p >> 1, kw = p & 1;
    float acc = 0.f;
    #pragma unroll 8
    for (int i = 0; i < COUT; ++i)
      acc += w_up[((c * COUT + i) * 2 + kh) * 2 + kw] * w_fuse[i * COUT + o];
    W_eff[idx] = acc;
  } else {
    int idx = (bid - 512) * 256 + threadIdx.x;   // 151552 total
    if (idx < 16384){ int r = idx >> 7, c = idx & 127; gW_inT[c * 128 + r] = gW_in[idx]; }
    else if (idx < 32768){ int i = idx - 16384; int r = i >> 7, c = i & 127; gW_gateT[c * 128 + r] = gW_gate[i]; }
    else if (idx < 49152){ int i = idx - 32768; int r = i >> 7, c = i & 127; gW_outT[c * 128 + r] = gW_out[i]; }
    else if (idx < 114688){ int i = idx - 49152; int r = i >> 7, c = i & 127; m_WinT[c * 512 + r] = m_Win[i]; }
    else if (idx < 147456){ int i = idx - 114688; int r = i >> 8, c = i & 255; m_WoutT[c * 128 + r] = m_Wout[i]; }
    else if (idx < 151552){ int i = idx - 147456; Aexp[i] = -expf(m_Alog[i]) * L2E; }
  }
}

// ---------- fused tokens: o-pair x px-pair outer product (512 thr, grid 512) ----------
__global__ __launch_bounds__(512, 8) void k_fused(const float* __restrict__ inp,
                        const float* __restrict__ skip,
                        const float* __restrict__ W_eff, const float* __restrict__ w_fuse,
                        float* __restrict__ fusedT, float* __restrict__ partials1){
  int bid = blockIdx.x;            // b*256 + h*4 + wt
  int wt = bid & 3;
  int h  = (bid >> 2) & 63;
  int b  = bid >> 8;
  int t  = threadIdx.x;            // 512
  int oP = t & 63, o0 = oP * 2;    // channel pair
  int g  = t >> 6;                 // 0..7 -> pixel pair 2g, 2g+1

  __shared__ float sIn[256 * 8];
  __shared__ float sSk[128 * 16];
  __shared__ float sS[128 * 9], sQ[128 * 9];   // [c][g], pitch 9
  int hi = h >> 1;
  int wi0 = wt * 8;
  #pragma unroll
  for (int k = 0; k < 4; ++k){
    int e = k * 512 + t;
    int c = e >> 3, wl = e & 7;
    sIn[e] = inp[((b * 256 + c) * 32 + hi) * 32 + wi0 + wl];
  }
  #pragma unroll
  for (int k = 0; k < 4; ++k){
    int e = k * 512 + t;
    int i = e >> 4, wl2 = e & 15;
    sSk[e] = skip[((b * 128 + i) * 64 + h) * 64 + wt * 16 + wl2];
  }
  __syncthreads();

  // a[px][o]: px0 = 2g (even -> parity plane p0), px1 = 2g+1 (p0+1)
  float a00 = 0.f, a01 = 0.f, a10 = 0.f, a11 = 0.f;
  int p0 = (h & 1) * 2;
  const float* w0p = W_eff + (size_t)p0 * 256 * 128 + o0;
  for (int c = 0; c < 256; ++c){
    float2 w0 = *(const float2*)&w0p[c * 128];
    float2 w1 = *(const float2*)&w0p[c * 128 + 32768];
    float x = sIn[c * 8 + g];     // both px share input col g
    a00 += x * w0.x; a01 += x * w0.y;
    a10 += x * w1.x; a11 += x * w1.y;
  }
  for (int i = 0; i < 128; ++i){
    float2 wf = *(const float2*)&w_fuse[(128 + i) * 128 + o0];
    float s0 = sSk[i * 16 + 2 * g];
    float s1 = sSk[i * 16 + 2 * g + 1];
    a00 += s0 * wf.x; a01 += s0 * wf.y;
    a10 += s1 * wf.x; a11 += s1 * wf.y;
  }
  {
    int w0i = wt * 16 + 2 * g;
    size_t r0 = ((size_t)(b * 4096 + h * 64 + w0i)) * 128 + o0;
    float2 v0; v0.x = a00; v0.y = a01;
    float2 v1; v1.x = a10; v1.y = a11;
    *(float2*)&fusedT[r0] = v0;
    *(float2*)&fusedT[r0 + 128] = v1;
  }
  // per-channel partial stats: channel o0 <- a00,a10 ; channel o1 <- a01,a11
  sS[o0 * 9 + g] = a00 + a10;
  sQ[o0 * 9 + g] = a00 * a00 + a10 * a10;
  sS[(o0 + 1) * 9 + g] = a01 + a11;
  sQ[(o0 + 1) * 9 + g] = a01 * a01 + a11 * a11;
  __syncthreads();
  if (t < 128){
    float S = 0.f, Q = 0.f;
    #pragma unroll
    for (int r = 0; r < 8; ++r){ S += sS[t * 9 + r]; Q += sQ[t * 9 + r]; }
    partials1[(size_t)bid * 256 + t * 2]     = S;
    partials1[(size_t)bid * 256 + t * 2 + 1] = Q;
  }
}

// ---------- reduce partials -> mu, rs ----------
__global__ __launch_bounds__(256) void k_stats2(const float* __restrict__ partials, int nb,
                         float cnt, float* __restrict__ mu, float* __restrict__ rs){
  int b = blockIdx.x;
  int t = threadIdx.x;
  int c = t & 127, half = t >> 7;
  int n2 = nb >> 1;
  float S = 0.f, Q = 0.f;
  for (int k = half * n2; k < (half + 1) * n2; ++k){
    S += partials[(size_t)(b * nb + k) * 256 + c * 2];
    Q += partials[(size_t)(b * nb + k) * 256 + c * 2 + 1];
  }
  __shared__ float sS[256], sQ[256];
  sS[t] = S; sQ[t] = Q;
  __syncthreads();
  if (t < 128){
    float Sa = sS[t] + sS[t + 128], Qa = sQ[t] + sQ[t + 128];
    float m = Sa / cnt;
    mu[b * 128 + t] = m;
    rs[b * 128 + t] = rsqrtf(Qa / cnt - m * m + 1e-5f);
  }
}

// ---------- front: norm+leaky -> (tok2, z) -> LN -> xz GEMM (8 toks, 512 thr, grid 1024) ----------
__global__ __launch_bounds__(512, 8) void k_front(const float* __restrict__ xt,
                      const float* __restrict__ mu1, const float* __restrict__ rs1,
                      const float* __restrict__ gW_inT, const float* __restrict__ gW_gateT,
                      const float* __restrict__ gb_gate,
                      const float* __restrict__ ln_g, const float* __restrict__ ln_b,
                      const float* __restrict__ m_WinT,
                      float* __restrict__ tok2, float* __restrict__ zb,
                      float* __restrict__ xm, float* __restrict__ zs){
  int tok0 = blockIdx.x * 8;
  int b = tok0 >> 12;
  int t = threadIdx.x;
  __shared__ float xn[128 * 8];    // [c][tok]
  __shared__ float tn[128 * 8];
  __shared__ float aT[8 * 132];    // [tok][o]
  __shared__ float sMu[8], sRs[8];

  #pragma unroll
  for (int k = 0; k < 2; ++k){
    int e = k * 512 + t;
    int tok = e >> 7, c = e & 127;
    float v = xt[(size_t)(tok0 + tok) * 128 + c];
    v = (v - mu1[b * 128 + c]) * rs1[b * 128 + c];
    v = v >= 0.f ? v : 0.01f * v;
    xn[c * 8 + tok] = v;
  }
  __syncthreads();

  int o = t & 127, th = t >> 7;
  float accA[2], accG[2];
  accA[0] = accA[1] = accG[0] = accG[1] = 0.f;
  for (int c = 0; c < 128; ++c){
    float wa = gW_inT[c * 128 + o];
    float wg = gW_gateT[c * 128 + o];
    float x0 = xn[c * 8 + th * 2], x1 = xn[c * 8 + th * 2 + 1];
    accA[0] += x0 * wa; accA[1] += x1 * wa;
    accG[0] += x0 * wg; accG[1] += x1 * wg;
  }
  float gb = gb_gate[o];
  #pragma unroll
  for (int j = 0; j < 2; ++j){
    int tok = th * 2 + j;
    tok2[(size_t)(tok0 + tok) * 128 + o] = accA[j];
    zb[(size_t)(tok0 + tok) * 128 + o] = sigm_(silu_(accG[j] + gb));
    aT[tok * 132 + o] = accA[j];
  }
  __syncthreads();

  if (t < 128){
    int tok = t >> 4, i = t & 15;
    float s = 0.f, q = 0.f;
    #pragma unroll
    for (int j = 0; j < 8; ++j){ float a = aT[tok * 132 + i * 8 + j]; s += a; q += a * a; }
    s += __shfl_down(s, 8, 16); q += __shfl_down(q, 8, 16);
    s += __shfl_down(s, 4, 16); q += __shfl_down(q, 4, 16);
    s += __shfl_down(s, 2, 16); q += __shfl_down(q, 2, 16);
    s += __shfl_down(s, 1, 16); q += __shfl_down(q, 1, 16);
    if (i == 0){
      float m = s / 128.f;
      sMu[tok] = m;
      sRs[tok] = rsqrtf(q / 128.f - m * m + 1e-5f);
    }
  }
  __syncthreads();
  #pragma unroll
  for (int k = 0; k < 2; ++k){
    int e = k * 512 + t;
    int tok = e >> 7, c = e & 127;
    tn[c * 8 + tok] = (aT[tok * 132 + c] - sMu[tok]) * sRs[tok] * ln_g[c] + ln_b[c];
  }
  __syncthreads();

  float a0[8];
  #pragma unroll
  for (int j = 0; j < 8; ++j) a0[j] = 0.f;
  for (int c = 0; c < 128; ++c){
    float w = m_WinT[c * 512 + t];
    float4 x0 = *(const float4*)&tn[c * 8];
    float4 x1 = *(const float4*)&tn[c * 8 + 4];
    a0[0] += x0.x * w; a0[1] += x0.y * w; a0[2] += x0.z * w; a0[3] += x0.w * w;
    a0[4] += x1.x * w; a0[5] += x1.y * w; a0[6] += x1.z * w; a0[7] += x1.w * w;
  }
  if (t < 256){
    #pragma unroll
    for (int j = 0; j < 8; ++j)
      xm[(size_t)(tok0 + j) * 256 + t] = a0[j];
  } else {
    #pragma unroll
    for (int j = 0; j < 8; ++j)
      zs[(size_t)(tok0 + j) * 256 + (t - 256)] = silu_(a0[j]);
  }
}

// ---------- mid: conv -> x_dbl(LDS weights) -> dt(once) -> local scan  (1024 thr, grid 512) ----------
__global__ __launch_bounds__(1024, 2) void k_mid(const float* __restrict__ xm,
                    const float* __restrict__ cw, const float* __restrict__ cb,
                    const float* __restrict__ m_Wx, const float* __restrict__ m_Wdt,
                    const float* __restrict__ m_bdt, const float* __restrict__ Aexp,
                    float* __restrict__ xcb, float* __restrict__ dtb,
                    float* __restrict__ Bmb, float* __restrict__ Cmb,
                    float* __restrict__ chunkA, float* __restrict__ chunkH){
  int ch = blockIdx.x & (SC_NC - 1), b = blockIdx.x >> 8;
  int l0 = ch * SC_T;
  int tok0 = b * LL + l0;
  int t = threadIdx.x;
  __shared__ float sWx[40 * WXP];     // 41.6 KB
  __shared__ float sxc[SC_T * SXP];   // 16.6 KB
  __shared__ float sdt[SC_T * 256];   // 16 KB
  __shared__ float sdbl[SC_T * 40];   // 2.5 KB

  #pragma unroll
  for (int u = 0; u < 10; ++u){
    int e = u * 1024 + t;
    int j = e >> 8, k = e & 255;
    sWx[j * WXP + k] = m_Wx[e];
  }

  {
    int d = t & 255, q = t >> 8;
    float xr[7];
    #pragma unroll
    for (int r = 0; r < 7; ++r){
      int l = l0 + q * 4 - 3 + r;
      xr[r] = (l >= 0) ? xm[(size_t)(b * LL + l) * 256 + d] : 0.f;
    }
    float4 cwv = *(const float4*)&cw[d * 4];
    float cbv = cb[d];
    #pragma unroll
    for (int j = 0; j < 4; ++j){
      float a = cbv + xr[j] * cwv.x + xr[j + 1] * cwv.y + xr[j + 2] * cwv.z + xr[j + 3] * cwv.w;
      a = silu_(a);
      sxc[(q * 4 + j) * SXP + d] = a;
    }
  }
  __syncthreads();

  {
    int tok = t >> 6, d0 = (t & 63) * 4;
    *(float4*)&xcb[(size_t)(tok0 + tok) * 256 + d0] = *(const float4*)&sxc[tok * SXP + d0];
  }

  if (t < 640){
    int i, tok;
    if (t < 512){ i = 8 + (t & 31); tok = t >> 5; }
    else        { int u = t - 512; i = u & 7; tok = u >> 3; }
    const float4* wr = (const float4*)&sWx[i * WXP];
    const float4* xr = (const float4*)&sxc[tok * SXP];
    float ac[4];
    #pragma unroll
    for (int c4 = 0; c4 < 4; ++c4){
      float s0 = 0.f, s1 = 0.f, s2 = 0.f, s3 = 0.f;
      #pragma unroll
      for (int k4 = 0; k4 < 16; ++k4){
        float4 w = wr[c4 * 16 + k4];
        float4 x = xr[c4 * 16 + k4];
        s0 += x.x * w.x; s1 += x.y * w.y; s2 += x.z * w.z; s3 += x.w * w.w;
      }
      ac[c4] = (s0 + s1) + (s2 + s3);
    }
    float a = (ac[0] + ac[1]) + (ac[2] + ac[3]);
    sdbl[tok * 40 + i] = a;
    if (t < 512){
      int ii = i - 8;
      if (ii < 16) Bmb[(size_t)(tok0 + tok) * 16 + ii] = a;
      else         Cmb[(size_t)(tok0 + tok) * 16 + (ii - 16)] = a;
    }
  }
  __syncthreads();

  {
    int d = t & 255;
    float4 wd0 = *(const float4*)&m_Wdt[d * 8];
    float4 wd1 = *(const float4*)&m_Wdt[d * 8 + 4];
    float bdt = m_bdt[d];
    int tq = t >> 8;
    #pragma unroll
    for (int k = 0; k < 4; ++k){
      int tok = k * 4 + tq;
      const float4* dp = (const float4*)&sdbl[tok * 40];
      float4 d0 = dp[0], d1 = dp[1];
      float dtr = bdt + d0.x * wd0.x + d0.y * wd0.y + d0.z * wd0.z + d0.w * wd0.w
                      + d1.x * wd1.x + d1.y * wd1.y + d1.z * wd1.z + d1.w * wd1.w;
      sdt[tok * 256 + d] = softplus_(dtr);
    }
  }
  __syncthreads();

  {
    int tok = t >> 6, d0 = (t & 63) * 4;
    *(float4*)&dtb[(size_t)(tok0 + tok) * 256 + d0] = *(const float4*)&sdt[tok * 256 + d0];
  }

  {
    int d = t & 255, sq = t >> 8;
    float4 Av = *(const float4*)&Aexp[d * 16 + sq * 4];   // pre-scaled by log2e
    float A0 = Av.x, A1 = Av.y, A2 = Av.z, A3 = Av.w;
    float h0 = 0.f, h1 = 0.f, h2 = 0.f, h3 = 0.f;
    float sumdt = 0.f;
    #pragma unroll 4
    for (int j = 0; j < SC_T; ++j){
      float dt = sdt[j * 256 + d];
      sumdt += dt;
      float u = dt * sxc[j * SXP + d];
      float4 bv = *(const float4*)&sdbl[j * 40 + 8 + sq * 4];
      h0 = ex2_(dt * A0) * h0 + u * bv.x;
      h1 = ex2_(dt * A1) * h1 + u * bv.y;
      h2 = ex2_(dt * A2) * h2 + u * bv.z;
      h3 = ex2_(dt * A3) * h3 + u * bv.w;
    }
    size_t base = ((size_t)(b * SC_NC + ch)) * 4096 + d * 16 + sq * 4;
    float4 va, vh;
    va.x = ex2_(A0 * sumdt); va.y = ex2_(A1 * sumdt);
    va.z = ex2_(A2 * sumdt); va.w = ex2_(A3 * sumdt);
    vh.x = h0; vh.y = h1; vh.z = h2; vh.w = h3;
    *(float4*)&chunkA[base] = va;
    *(float4*)&chunkH[base] = vh;
  }
}

// ---------- scanB1: super-summaries over CPS chunks ----------
__global__ __launch_bounds__(256) void k_scanB1(const float* __restrict__ chunkA,
                        const float* __restrict__ chunkH,
                        float* __restrict__ superA, float* __restrict__ superH){
  int blk = blockIdx.x;                 // 2 * NSUP * 16
  int ds = (blk & 15) * 256 + threadIdx.x;
  int sc = (blk >> 4) & (NSUP - 1);
  int b  = blk >> 8;
  float sA = 1.f, sH = 0.f;
  for (int j = 0; j < CPS; ++j){
    size_t idx = ((size_t)(b * SC_NC + sc * CPS + j)) * 4096 + ds;
    float A = chunkA[idx], H = chunkH[idx];
    sA = A * sA;
    sH = A * sH + H;
  }
  size_t o = ((size_t)(b * NSUP + sc)) * 4096 + ds;
  superA[o] = sA; superH[o] = sH;
}

// ---------- scanB2: serial combine over supers; supercarry in place ----------
__global__ __launch_bounds__(256) void k_scanB2(const float* __restrict__ superA,
                        float* __restrict__ superH){
  int gid = blockIdx.x * 256 + threadIdx.x;  // 8192
  int ds = gid & 4095;
  int b = gid >> 12;
  float carry = 0.f;
  #pragma unroll
  for (int sc = 0; sc < NSUP; ++sc){
    size_t idx = ((size_t)(b * NSUP + sc)) * 4096 + ds;
    float A = superA[idx], H = superH[idx];
    superH[idx] = carry;
    carry = A * carry + H;
  }
}

// ---------- scanB3: walk chunks with supercarry; carry in place into chunkH ----------
__global__ __launch_bounds__(256) void k_scanB3(const float* __restrict__ chunkA,
                        float* __restrict__ chunkH, const float* __restrict__ superH){
  int blk = blockIdx.x;
  int ds = (blk & 15) * 256 + threadIdx.x;
  int sc = (blk >> 4) & (NSUP - 1);
  int b  = blk >> 8;
  float carry = superH[((size_t)(b * NSUP + sc)) * 4096 + ds];
  for (int j = 0; j < CPS; ++j){
    size_t idx = ((size_t)(b * SC_NC + sc * CPS + j)) * 4096 + ds;
    float A = chunkA[idx], H = chunkH[idx];
    chunkH[idx] = carry;
    carry = A * carry + H;
  }
}

// ---------- back: LDS-staged re-scan + cc-pair GEMMs -> residual + IN2 ----------
__global__ __launch_bounds__(1024, 2) void k_back(const float* __restrict__ dtb,
                        const float* __restrict__ xcb,
                        const float* __restrict__ Bmb, const float* __restrict__ Cmb,
                        const float* __restrict__ Aexp, const float* __restrict__ m_D,
                        const float* __restrict__ zs, const float* __restrict__ carryBuf,
                        const float* __restrict__ m_WoutT,
                        const float* __restrict__ zb, const float* __restrict__ gW_outT,
                        const float* __restrict__ xt, const float* __restrict__ tok2,
                        const float* __restrict__ mu1, const float* __restrict__ rs1,
                        float* __restrict__ outpre, float* __restrict__ partials2){
  int ch = blockIdx.x & (SC_NC - 1), b = blockIdx.x >> 8;
  int l0 = ch * SC_T;
  int tok0 = b * LL + l0;
  int t = threadIdx.x;
  __shared__ float sB[SC_T * 16], sC[SC_T * 16];   // 2 KB
  __shared__ float sdtH[8 * 256];                  // 8 KB
  __shared__ float sxcH[8 * 256];                  // 8 KB
  __shared__ float szsH[8 * 256];                  // 8 KB
  __shared__ float yT[SC_T * 256];                 // 16 KB [l][d]
  __shared__ float sv[SC_T * 128];                 // 8 KB [tok][c]
  __shared__ float sS[128 * 17], sQ[128 * 17];     // 17.4 KB [c][tok] pitch 17
  if (t < 256){
    sB[t] = Bmb[(size_t)tok0 * 16 + t];
    sC[t] = Cmb[(size_t)tok0 * 16 + t];
  }

  // scan phase: sq = t&3 (4 states), d = t>>2 (shfl-width-4 reduce)
  {
    int sq = t & 3, d = t >> 2;
    float4 Av = *(const float4*)&Aexp[d * 16 + sq * 4];   // pre-scaled by log2e
    float A0 = Av.x, A1 = Av.y, A2 = Av.z, A3 = Av.w;
    size_t cbase = ((size_t)(b * SC_NC + ch)) * 4096 + d * 16 + sq * 4;
    float4 hv = *(const float4*)&carryBuf[cbase];
    float h0 = hv.x, h1 = hv.y, h2 = hv.z, h3 = hv.w;
    float Dv = m_D[d];

    for (int half = 0; half < 2; ++half){
      __syncthreads();
      size_t base = (size_t)(tok0 + half * 8) * 256;
      for (int u = t; u < 1536; u += 1024){
        int buf = u >> 9, idx = u & 511;
        const float* src = (buf == 0) ? (dtb + base) : (buf == 1) ? (xcb + base) : (zs + base);
        float* dst = (buf == 0) ? sdtH : (buf == 1) ? sxcH : szsH;
        ((float4*)dst)[idx] = ((const float4*)src)[idx];
      }
      __syncthreads();
      #pragma unroll
      for (int l2 = 0; l2 < 8; ++l2){
        int l = half * 8 + l2;
        float dt = sdtH[l2 * 256 + d];
        float xc = sxcH[l2 * 256 + d];
        float u = dt * xc;
        float4 bv = *(const float4*)&sB[l * 16 + sq * 4];
        float4 cv = *(const float4*)&sC[l * 16 + sq * 4];
        h0 = ex2_(dt * A0) * h0 + u * bv.x;
        h1 = ex2_(dt * A1) * h1 + u * bv.y;
        h2 = ex2_(dt * A2) * h2 + u * bv.z;
        h3 = ex2_(dt * A3) * h3 + u * bv.w;
        float p = h0 * cv.x + h1 * cv.y + h2 * cv.z + h3 * cv.w;
        p += __shfl_xor(p, 1, 4);
        p += __shfl_xor(p, 2, 4);
        if (sq == 0){
          float zv = szsH[l2 * 256 + d];
          yT[l * 256 + d] = (p + xc * Dv) * zv;
        }
      }
    }
  }
  __syncthreads();

  // mout GEMM: cc-pair (cc0 = 2*(t&63)), tok = t>>6 (16 toks)
  int oP = t & 63, cc0 = oP * 2;
  int tok = t >> 6;
  float a0 = 0.f, a1 = 0.f;
  for (int dd = 0; dd < 256; ++dd){
    float2 w = *(const float2*)&m_WoutT[dd * 128 + cc0];
    float y = yT[tok * 256 + dd];
    a0 += y * w.x; a1 += y * w.y;
  }
  {
    float2 z = *(const float2*)&zb[(size_t)(tok0 + tok) * 128 + cc0];
    float2 v; v.x = a0 * z.x; v.y = a1 * z.y;
    *(float2*)&sv[tok * 128 + cc0] = v;
  }
  __syncthreads();

  // out proj GEMM
  float b0 = 0.f, b1 = 0.f;
  for (int ci = 0; ci < 128; ++ci){
    float2 w = *(const float2*)&gW_outT[ci * 128 + cc0];
    float s = sv[tok * 128 + ci];
    b0 += s * w.x; b1 += s * w.y;
  }
  {
    float2 muv = *(const float2*)&mu1[b * 128 + cc0];
    float2 rsv = *(const float2*)&rs1[b * 128 + cc0];
    size_t idx = (size_t)(tok0 + tok) * 128 + cc0;
    float2 xv = *(const float2*)&xt[idx];
    float2 t2 = *(const float2*)&tok2[idx];
    float xn0 = (xv.x - muv.x) * rsv.x; xn0 = xn0 >= 0.f ? xn0 : 0.01f * xn0;
    float xn1 = (xv.y - muv.y) * rsv.y; xn1 = xn1 >= 0.f ? xn1 : 0.01f * xn1;
    float v0 = xn0 + t2.x + b0;
    float v1 = xn1 + t2.y + b1;
    float2 ov; ov.x = v0; ov.y = v1;
    *(float2*)&outpre[idx] = ov;
    sS[cc0 * 17 + tok] = v0;       sQ[cc0 * 17 + tok] = v0 * v0;
    sS[(cc0 + 1) * 17 + tok] = v1; sQ[(cc0 + 1) * 17 + tok] = v1 * v1;
  }
  __syncthreads();
  if (t < 128){
    float S = 0.f, Q = 0.f;
    #pragma unroll
    for (int r = 0; r < 16; ++r){ S += sS[t * 17 + r]; Q += sQ[t * 17 + r]; }
    partials2[(size_t)blockIdx.x * 256 + t * 2]     = S;
    partials2[(size_t)blockIdx.x * 256 + t * 2 + 1] = Q;
  }
}

// ---------- final: instance-norm + NCHW transpose via LDS (grid 512) ----------
__global__ __launch_bounds__(256) void k_final(const float* __restrict__ outpre,
                        const float* __restrict__ mu,
                        const float* __restrict__ rs, float* __restrict__ out){
  int bid = blockIdx.x;            // b*256 + cg*128 + lg
  int lg = bid & 127, cg = (bid >> 7) & 1, b = bid >> 8;
  int t = threadIdx.x;
  __shared__ float sT[64 * 33];
  int l0 = lg * 32, c0 = cg * 64;
  #pragma unroll
  for (int k = 0; k < 8; ++k){
    int e = k * 256 + t;
    int l = e >> 6, cc = e & 63;
    float v = outpre[(size_t)(b * 4096 + l0 + l) * 128 + c0 + cc];
    v = (v - mu[b * 128 + c0 + cc]) * rs[b * 128 + c0 + cc];
    sT[cc * 33 + l] = v;
  }
  __syncthreads();
  #pragma unroll
  for (int k = 0; k < 8; ++k){
    int e = k * 256 + t;
    int cc = e >> 5, l = e & 31;
    out[((size_t)(b * 128 + c0 + cc)) * 4096 + l0 + l] = sT[cc * 33 + l];
  }
}

extern "C" void kernel_launch(void* const* d_in, const int* in_sizes, int n_in,
                              void* d_out, int out_size, void* d_ws, size_t ws_size,
                              hipStream_t stream){
  const float* inp    = (const float*)d_in[0];
  const float* skip   = (const float*)d_in[1];
  const float* w_up   = (const float*)d_in[2];
  const float* w_fuse = (const float*)d_in[3];
  const float* gW_in  = (const float*)d_in[4];
  const float* gW_gate= (const float*)d_in[5];
  const float* gb_gate= (const float*)d_in[6];
  const float* ln_g   = (const float*)d_in[7];
  const float* ln_b   = (const float*)d_in[8];
  const float* gW_out = (const float*)d_in[9];
  const float* m_Win  = (const float*)d_in[10];
  const float* m_convw= (const float*)d_in[11];
  const float* m_convb= (const float*)d_in[12];
  const float* m_Wx   = (const float*)d_in[13];
  const float* m_Wdt  = (const float*)d_in[14];
  const float* m_bdt  = (const float*)d_in[15];
  const float* m_Alog = (const float*)d_in[16];
  const float* m_D    = (const float*)d_in[17];
  const float* m_Wout = (const float*)d_in[18];
  float* out = (float*)d_out;

  float* ws = (float*)d_ws;
  float* W_eff    = ws;                        // 131072
  float* xt       = W_eff + 131072;            // 1048576
  float* tok2     = xt + 1048576;              // 1048576
  float* zb       = tok2 + 1048576;            // 1048576
  float* xmbuf    = zb + 1048576;              // 2097152 (xm, later outpre)
  float* zs       = xmbuf + 2097152;           // 2097152
  float* xcb      = zs + 2097152;              // 2097152
  float* dtb      = xcb + 2097152;             // 2097152
  float* Bmb      = dtb + 2097152;             // 131072
  float* Cmb      = Bmb + 131072;              // 131072
  float* chunkA   = Cmb + 131072;              // 2097152
  float* chunkH   = chunkA + 2097152;          // 2097152 (carry in place after B3)
  float* superA   = chunkH + 2097152;          // 131072
  float* superH   = superA + 131072;           // 131072 (supercarry after B2)
  float* partials = superH + 131072;           // 131072 (IN1, reused IN2)
  float* stats    = partials + 131072;         // 1024
  float* gW_inT   = stats + 1024;              // 16384
  float* gW_gateT = gW_inT + 16384;            // 16384
  float* gW_outT  = gW_gateT + 16384;          // 16384
  float* m_WinT   = gW_outT + 16384;           // 65536
  float* m_WoutT  = m_WinT + 65536;            // 32768
  float* AexpBuf  = m_WoutT + 32768;           // 4096

  float* mu1 = stats, *rs1 = stats + 256, *mu2 = stats + 512, *rs2 = stats + 768;
  float* xm = xmbuf;
  float* outpre = xmbuf;   // alias: xm dead after k_mid

  k_prep<<<1104, 256, 0, stream>>>(w_up, w_fuse, gW_in, gW_gate, gW_out, m_Win, m_Wout,
                                   m_Alog, W_eff, gW_inT, gW_gateT, gW_outT, m_WinT,
                                   m_WoutT, AexpBuf);

  k_fused<<<512, 512, 0, stream>>>(inp, skip, W_eff, w_fuse, xt, partials);
  k_stats2<<<2, 256, 0, stream>>>(partials, 256, 4096.f, mu1, rs1);

  k_front<<<1024, 512, 0, stream>>>(xt, mu1, rs1, gW_inT, gW_gateT, gb_gate, ln_g, ln_b,
                                    m_WinT, tok2, zb, xm, zs);
  k_mid<<<512, 1024, 0, stream>>>(xm, m_convw, m_convb, m_Wx, m_Wdt, m_bdt, AexpBuf,
                                  xcb, dtb, Bmb, Cmb, chunkA, chunkH);
  k_scanB1<<<512, 256, 0, stream>>>(chunkA, chunkH, superA, superH);
  k_scanB2<<<32, 256, 0, stream>>>(superA, superH);
  k_scanB3<<<512, 256, 0, stream>>>(chunkA, chunkH, superH);
  k_back<<<512, 1024, 0, stream>>>(dtb, xcb, Bmb, Cmb, AexpBuf, m_D, zs, chunkH,
                                   m_WoutT, zb, gW_outT, xt, tok2, mu1, rs1,
                                   outpre, partials);
  k_stats2<<<2, 256, 0, stream>>>(partials, 256, 4096.f, mu2, rs2);
  k_final<<<512, 256, 0, stream>>>(outpre, mu2, rs2, out);
}

// Round 14
// 213.587 us; speedup vs baseline: 1.5042x; 1.5042x over previous
//
#include <hip/hip_runtime.h>
#include <math.h>

#define BB 2
#define CIN 256
#define COUT 128
#define LL 4096
#define DI 256
#define DS 16

#define SC_T 16     // chunk length
#define SC_NC 256   // chunks per batch
#define SXP 260     // sxc pitch: bank step 4/row -> conflict-free
#define WXP 260     // sWx pitch
#define NSUP 16     // superchunks
#define CPS 16      // chunks per superchunk

#define L2E 1.44269504088896340736f
#define LN2 0.69314718055994530942f

// native transcendentals: v_exp_f32 (2^x), v_log_f32 (log2), v_rcp_f32
__device__ __forceinline__ float ex2_(float x){ return __builtin_amdgcn_exp2f(x); }
__device__ __forceinline__ float fexp_(float x){ return ex2_(x * L2E); }
__device__ __forceinline__ float rcp_(float x){ return __builtin_amdgcn_rcpf(x); }
__device__ __forceinline__ float silu_(float x){ return x * rcp_(1.f + fexp_(-x)); }
__device__ __forceinline__ float sigm_(float x){ return rcp_(1.f + fexp_(-x)); }
__device__ __forceinline__ float softplus_(float x){
  return (x > 20.f) ? x : LN2 * __builtin_amdgcn_logf(1.f + fexp_(x));
}

// ---------- prep: W_eff + all transposes + Aexp (one dispatch) ----------
__global__ __launch_bounds__(256) void k_prep(
    const float* __restrict__ w_up, const float* __restrict__ w_fuse,
    const float* __restrict__ gW_in, const float* __restrict__ gW_gate,
    const float* __restrict__ gW_out, const float* __restrict__ m_Win,
    const float* __restrict__ m_Wout, const float* __restrict__ m_Alog,
    float* __restrict__ W_eff,
    float* __restrict__ gW_inT, float* __restrict__ gW_gateT,
    float* __restrict__ gW_outT, float* __restrict__ m_WinT,
    float* __restrict__ m_WoutT, float* __restrict__ Aexp){
  int bid = blockIdx.x;
  if (bid < 512){
    int idx = bid * 256 + threadIdx.x;   // 4*256*128
    int o = idx & 127;
    int c = (idx >> 7) & 255;
    int p = idx >> 15;
    int kh = p >> 1, kw = p & 1;
    float acc = 0.f;
    #pragma unroll 8
    for (int i = 0; i < COUT; ++i)
      acc += w_up[((c * COUT + i) * 2 + kh) * 2 + kw] * w_fuse[i * COUT + o];
    W_eff[idx] = acc;
  } else {
    int idx = (bid - 512) * 256 + threadIdx.x;   // 151552 total
    if (idx < 16384){ int r = idx >> 7, c = idx & 127; gW_inT[c * 128 + r] = gW_in[idx]; }
    else if (idx < 32768){ int i = idx - 16384; int r = i >> 7, c = i & 127; gW_gateT[c * 128 + r] = gW_gate[i]; }
    else if (idx < 49152){ int i = idx - 32768; int r = i >> 7, c = i & 127; gW_outT[c * 128 + r] = gW_out[i]; }
    else if (idx < 114688){ int i = idx - 49152; int r = i >> 7, c = i & 127; m_WinT[c * 512 + r] = m_Win[i]; }
    else if (idx < 147456){ int i = idx - 114688; int r = i >> 8, c = i & 255; m_WoutT[c * 128 + r] = m_Wout[i]; }
    else if (idx < 151552){ int i = idx - 147456; Aexp[i] = -expf(m_Alog[i]) * L2E; }
  }
}

// ---------- fused tokens (16-px tile, grid 512, 512 thr) + partial stats ----------
__global__ __launch_bounds__(512, 8) void k_fused(const float* __restrict__ inp,
                        const float* __restrict__ skip,
                        const float* __restrict__ W_eff, const float* __restrict__ w_fuse,
                        float* __restrict__ fusedT, float* __restrict__ partials1){
  int bid = blockIdx.x;            // b*256 + h*4 + wt
  int wt = bid & 3;
  int h  = (bid >> 2) & 63;
  int b  = bid >> 8;
  int t  = threadIdx.x;            // 512
  int o  = t & 127;
  int g  = t >> 7;                 // 0..3 -> 4 pixels each

  __shared__ float sIn[256 * 8];
  __shared__ float sSk[128 * 16];
  __shared__ float sS[512], sQ[512];
  int hi = h >> 1;
  int wi0 = wt * 8;
  #pragma unroll
  for (int k = 0; k < 4; ++k){
    int e = k * 512 + t;
    int c = e >> 3, wl = e & 7;
    sIn[e] = inp[((b * 256 + c) * 32 + hi) * 32 + wi0 + wl];
  }
  #pragma unroll
  for (int k = 0; k < 4; ++k){
    int e = k * 512 + t;
    int i = e >> 4, wl2 = e & 15;
    sSk[e] = skip[((b * 128 + i) * 64 + h) * 64 + wt * 16 + wl2];
  }
  __syncthreads();

  float acc[4];
  #pragma unroll
  for (int j = 0; j < 4; ++j) acc[j] = 0.f;

  for (int par = 0; par < 2; ++par){
    int p = (h & 1) * 2 + par;
    const float* wptr = W_eff + (size_t)p * 256 * 128 + o;
    for (int c = 0; c < 256; ++c){
      float we = wptr[c * 128];
      acc[par]     += sIn[c * 8 + g * 2]     * we;
      acc[2 + par] += sIn[c * 8 + g * 2 + 1] * we;
    }
  }
  for (int i = 0; i < 128; ++i){
    float wf = w_fuse[(128 + i) * 128 + o];
    #pragma unroll
    for (int j = 0; j < 4; ++j)
      acc[j] += sSk[i * 16 + g * 4 + j] * wf;
  }
  float s4 = 0.f, q4 = 0.f;
  #pragma unroll
  for (int j = 0; j < 4; ++j){
    int w = wt * 16 + g * 4 + j;
    fusedT[((size_t)(b * 4096 + h * 64 + w)) * 128 + o] = acc[j];
    s4 += acc[j]; q4 += acc[j] * acc[j];
  }
  sS[t] = s4; sQ[t] = q4;
  __syncthreads();
  if (t < 128){
    partials1[(size_t)bid * 256 + t * 2]     = sS[t] + sS[t + 128] + sS[t + 256] + sS[t + 384];
    partials1[(size_t)bid * 256 + t * 2 + 1] = sQ[t] + sQ[t + 128] + sQ[t + 256] + sQ[t + 384];
  }
}

// ---------- reduce partials -> mu, rs ----------
__global__ __launch_bounds__(256) void k_stats2(const float* __restrict__ partials, int nb,
                         float cnt, float* __restrict__ mu, float* __restrict__ rs){
  int b = blockIdx.x;
  int t = threadIdx.x;
  int c = t & 127, half = t >> 7;
  int n2 = nb >> 1;
  float S = 0.f, Q = 0.f;
  for (int k = half * n2; k < (half + 1) * n2; ++k){
    S += partials[(size_t)(b * nb + k) * 256 + c * 2];
    Q += partials[(size_t)(b * nb + k) * 256 + c * 2 + 1];
  }
  __shared__ float sS[256], sQ[256];
  sS[t] = S; sQ[t] = Q;
  __syncthreads();
  if (t < 128){
    float Sa = sS[t] + sS[t + 128], Qa = sQ[t] + sQ[t + 128];
    float m = Sa / cnt;
    mu[b * 128 + t] = m;
    rs[b * 128 + t] = rsqrtf(Qa / cnt - m * m + 1e-5f);
  }
}

// ---------- front: norm+leaky -> (tok2, z) -> LN -> xz GEMM (8 toks, 512 thr, grid 1024) ----------
__global__ __launch_bounds__(512, 8) void k_front(const float* __restrict__ xt,
                      const float* __restrict__ mu1, const float* __restrict__ rs1,
                      const float* __restrict__ gW_inT, const float* __restrict__ gW_gateT,
                      const float* __restrict__ gb_gate,
                      const float* __restrict__ ln_g, const float* __restrict__ ln_b,
                      const float* __restrict__ m_WinT,
                      float* __restrict__ tok2, float* __restrict__ zb,
                      float* __restrict__ xm, float* __restrict__ zs){
  int tok0 = blockIdx.x * 8;
  int b = tok0 >> 12;
  int t = threadIdx.x;
  __shared__ float xn[128 * 8];    // [c][tok]
  __shared__ float tn[128 * 8];
  __shared__ float aT[8 * 132];    // [tok][o]
  __shared__ float sMu[8], sRs[8];

  #pragma unroll
  for (int k = 0; k < 2; ++k){
    int e = k * 512 + t;
    int tok = e >> 7, c = e & 127;
    float v = xt[(size_t)(tok0 + tok) * 128 + c];
    v = (v - mu1[b * 128 + c]) * rs1[b * 128 + c];
    v = v >= 0.f ? v : 0.01f * v;
    xn[c * 8 + tok] = v;
  }
  __syncthreads();

  int o = t & 127, th = t >> 7;
  float accA[2], accG[2];
  accA[0] = accA[1] = accG[0] = accG[1] = 0.f;
  for (int c = 0; c < 128; ++c){
    float wa = gW_inT[c * 128 + o];
    float wg = gW_gateT[c * 128 + o];
    float x0 = xn[c * 8 + th * 2], x1 = xn[c * 8 + th * 2 + 1];
    accA[0] += x0 * wa; accA[1] += x1 * wa;
    accG[0] += x0 * wg; accG[1] += x1 * wg;
  }
  float gb = gb_gate[o];
  #pragma unroll
  for (int j = 0; j < 2; ++j){
    int tok = th * 2 + j;
    tok2[(size_t)(tok0 + tok) * 128 + o] = accA[j];
    zb[(size_t)(tok0 + tok) * 128 + o] = sigm_(silu_(accG[j] + gb));
    aT[tok * 132 + o] = accA[j];
  }
  __syncthreads();

  if (t < 128){
    int tok = t >> 4, i = t & 15;
    float s = 0.f, q = 0.f;
    #pragma unroll
    for (int j = 0; j < 8; ++j){ float a = aT[tok * 132 + i * 8 + j]; s += a; q += a * a; }
    s += __shfl_down(s, 8, 16); q += __shfl_down(q, 8, 16);
    s += __shfl_down(s, 4, 16); q += __shfl_down(q, 4, 16);
    s += __shfl_down(s, 2, 16); q += __shfl_down(q, 2, 16);
    s += __shfl_down(s, 1, 16); q += __shfl_down(q, 1, 16);
    if (i == 0){
      float m = s / 128.f;
      sMu[tok] = m;
      sRs[tok] = rsqrtf(q / 128.f - m * m + 1e-5f);
    }
  }
  __syncthreads();
  #pragma unroll
  for (int k = 0; k < 2; ++k){
    int e = k * 512 + t;
    int tok = e >> 7, c = e & 127;
    tn[c * 8 + tok] = (aT[tok * 132 + c] - sMu[tok]) * sRs[tok] * ln_g[c] + ln_b[c];
  }
  __syncthreads();

  float a0[8];
  #pragma unroll
  for (int j = 0; j < 8; ++j) a0[j] = 0.f;
  for (int c = 0; c < 128; ++c){
    float w = m_WinT[c * 512 + t];
    float4 x0 = *(const float4*)&tn[c * 8];
    float4 x1 = *(const float4*)&tn[c * 8 + 4];
    a0[0] += x0.x * w; a0[1] += x0.y * w; a0[2] += x0.z * w; a0[3] += x0.w * w;
    a0[4] += x1.x * w; a0[5] += x1.y * w; a0[6] += x1.z * w; a0[7] += x1.w * w;
  }
  if (t < 256){
    #pragma unroll
    for (int j = 0; j < 8; ++j)
      xm[(size_t)(tok0 + j) * 256 + t] = a0[j];
  } else {
    #pragma unroll
    for (int j = 0; j < 8; ++j)
      zs[(size_t)(tok0 + j) * 256 + (t - 256)] = silu_(a0[j]);
  }
}

// ---------- mid: conv -> x_dbl(LDS weights) -> dt(once) -> local scan  (1024 thr, grid 512) ----------
__global__ __launch_bounds__(1024, 2) void k_mid(const float* __restrict__ xm,
                    const float* __restrict__ cw, const float* __restrict__ cb,
                    const float* __restrict__ m_Wx, const float* __restrict__ m_Wdt,
                    const float* __restrict__ m_bdt, const float* __restrict__ Aexp,
                    float* __restrict__ xcb, float* __restrict__ dtb,
                    float* __restrict__ Bmb, float* __restrict__ Cmb,
                    float* __restrict__ chunkA, float* __restrict__ chunkH){
  int ch = blockIdx.x & (SC_NC - 1), b = blockIdx.x >> 8;
  int l0 = ch * SC_T;
  int tok0 = b * LL + l0;
  int t = threadIdx.x;
  __shared__ float sWx[40 * WXP];     // 41.6 KB
  __shared__ float sxc[SC_T * SXP];   // 16.6 KB
  __shared__ float sdt[SC_T * 256];   // 16 KB
  __shared__ float sdbl[SC_T * 40];   // 2.5 KB

  #pragma unroll
  for (int u = 0; u < 10; ++u){
    int e = u * 1024 + t;
    int j = e >> 8, k = e & 255;
    sWx[j * WXP + k] = m_Wx[e];
  }

  {
    int d = t & 255, q = t >> 8;
    float xr[7];
    #pragma unroll
    for (int r = 0; r < 7; ++r){
      int l = l0 + q * 4 - 3 + r;
      xr[r] = (l >= 0) ? xm[(size_t)(b * LL + l) * 256 + d] : 0.f;
    }
    float4 cwv = *(const float4*)&cw[d * 4];
    float cbv = cb[d];
    #pragma unroll
    for (int j = 0; j < 4; ++j){
      float a = cbv + xr[j] * cwv.x + xr[j + 1] * cwv.y + xr[j + 2] * cwv.z + xr[j + 3] * cwv.w;
      a = silu_(a);
      sxc[(q * 4 + j) * SXP + d] = a;
    }
  }
  __syncthreads();

  {
    int tok = t >> 6, d0 = (t & 63) * 4;
    *(float4*)&xcb[(size_t)(tok0 + tok) * 256 + d0] = *(const float4*)&sxc[tok * SXP + d0];
  }

  if (t < 640){
    int i, tok;
    if (t < 512){ i = 8 + (t & 31); tok = t >> 5; }
    else        { int u = t - 512; i = u & 7; tok = u >> 3; }
    const float4* wr = (const float4*)&sWx[i * WXP];
    const float4* xr = (const float4*)&sxc[tok * SXP];
    float ac[4];
    #pragma unroll
    for (int c4 = 0; c4 < 4; ++c4){
      float s0 = 0.f, s1 = 0.f, s2 = 0.f, s3 = 0.f;
      #pragma unroll
      for (int k4 = 0; k4 < 16; ++k4){
        float4 w = wr[c4 * 16 + k4];
        float4 x = xr[c4 * 16 + k4];
        s0 += x.x * w.x; s1 += x.y * w.y; s2 += x.z * w.z; s3 += x.w * w.w;
      }
      ac[c4] = (s0 + s1) + (s2 + s3);
    }
    float a = (ac[0] + ac[1]) + (ac[2] + ac[3]);
    sdbl[tok * 40 + i] = a;
    if (t < 512){
      int ii = i - 8;
      if (ii < 16) Bmb[(size_t)(tok0 + tok) * 16 + ii] = a;
      else         Cmb[(size_t)(tok0 + tok) * 16 + (ii - 16)] = a;
    }
  }
  __syncthreads();

  {
    int d = t & 255;
    float4 wd0 = *(const float4*)&m_Wdt[d * 8];
    float4 wd1 = *(const float4*)&m_Wdt[d * 8 + 4];
    float bdt = m_bdt[d];
    int tq = t >> 8;
    #pragma unroll
    for (int k = 0; k < 4; ++k){
      int tok = k * 4 + tq;
      const float4* dp = (const float4*)&sdbl[tok * 40];
      float4 d0 = dp[0], d1 = dp[1];
      float dtr = bdt + d0.x * wd0.x + d0.y * wd0.y + d0.z * wd0.z + d0.w * wd0.w
                      + d1.x * wd1.x + d1.y * wd1.y + d1.z * wd1.z + d1.w * wd1.w;
      sdt[tok * 256 + d] = softplus_(dtr);
    }
  }
  __syncthreads();

  {
    int tok = t >> 6, d0 = (t & 63) * 4;
    *(float4*)&dtb[(size_t)(tok0 + tok) * 256 + d0] = *(const float4*)&sdt[tok * 256 + d0];
  }

  {
    int d = t & 255, sq = t >> 8;
    float4 Av = *(const float4*)&Aexp[d * 16 + sq * 4];   // pre-scaled by log2e
    float A0 = Av.x, A1 = Av.y, A2 = Av.z, A3 = Av.w;
    float h0 = 0.f, h1 = 0.f, h2 = 0.f, h3 = 0.f;
    float sumdt = 0.f;
    #pragma unroll 4
    for (int j = 0; j < SC_T; ++j){
      float dt = sdt[j * 256 + d];
      sumdt += dt;
      float u = dt * sxc[j * SXP + d];
      float4 bv = *(const float4*)&sdbl[j * 40 + 8 + sq * 4];
      h0 = ex2_(dt * A0) * h0 + u * bv.x;
      h1 = ex2_(dt * A1) * h1 + u * bv.y;
      h2 = ex2_(dt * A2) * h2 + u * bv.z;
      h3 = ex2_(dt * A3) * h3 + u * bv.w;
    }
    size_t base = ((size_t)(b * SC_NC + ch)) * 4096 + d * 16 + sq * 4;
    float4 va, vh;
    va.x = ex2_(A0 * sumdt); va.y = ex2_(A1 * sumdt);
    va.z = ex2_(A2 * sumdt); va.w = ex2_(A3 * sumdt);
    vh.x = h0; vh.y = h1; vh.z = h2; vh.w = h3;
    *(float4*)&chunkA[base] = va;
    *(float4*)&chunkH[base] = vh;
  }
}

// ---------- scanB1: super-summaries over CPS chunks ----------
__global__ __launch_bounds__(256) void k_scanB1(const float* __restrict__ chunkA,
                        const float* __restrict__ chunkH,
                        float* __restrict__ superA, float* __restrict__ superH){
  int blk = blockIdx.x;                 // 2 * NSUP * 16
  int ds = (blk & 15) * 256 + threadIdx.x;
  int sc = (blk >> 4) & (NSUP - 1);
  int b  = blk >> 8;
  float sA = 1.f, sH = 0.f;
  for (int j = 0; j < CPS; ++j){
    size_t idx = ((size_t)(b * SC_NC + sc * CPS + j)) * 4096 + ds;
    float A = chunkA[idx], H = chunkH[idx];
    sA = A * sA;
    sH = A * sH + H;
  }
  size_t o = ((size_t)(b * NSUP + sc)) * 4096 + ds;
  superA[o] = sA; superH[o] = sH;
}

// ---------- scanB2: serial combine over supers; supercarry in place ----------
__global__ __launch_bounds__(256) void k_scanB2(const float* __restrict__ superA,
                        float* __restrict__ superH){
  int gid = blockIdx.x * 256 + threadIdx.x;  // 8192
  int ds = gid & 4095;
  int b = gid >> 12;
  float carry = 0.f;
  #pragma unroll
  for (int sc = 0; sc < NSUP; ++sc){
    size_t idx = ((size_t)(b * NSUP + sc)) * 4096 + ds;
    float A = superA[idx], H = superH[idx];
    superH[idx] = carry;
    carry = A * carry + H;
  }
}

// ---------- scanB3: walk chunks with supercarry; carry in place into chunkH ----------
__global__ __launch_bounds__(256) void k_scanB3(const float* __restrict__ chunkA,
                        float* __restrict__ chunkH, const float* __restrict__ superH){
  int blk = blockIdx.x;
  int ds = (blk & 15) * 256 + threadIdx.x;
  int sc = (blk >> 4) & (NSUP - 1);
  int b  = blk >> 8;
  float carry = superH[((size_t)(b * NSUP + sc)) * 4096 + ds];
  for (int j = 0; j < CPS; ++j){
    size_t idx = ((size_t)(b * SC_NC + sc * CPS + j)) * 4096 + ds;
    float A = chunkA[idx], H = chunkH[idx];
    chunkH[idx] = carry;
    carry = A * carry + H;
  }
}

// ---------- back: LDS-staged re-scan + mout -> gate -> out proj -> residual + IN2 ----------
__global__ __launch_bounds__(1024, 8) void k_back(const float* __restrict__ dtb,
                        const float* __restrict__ xcb,
                        const float* __restrict__ Bmb, const float* __restrict__ Cmb,
                        const float* __restrict__ Aexp, const float* __restrict__ m_D,
                        const float* __restrict__ zs, const float* __restrict__ carryBuf,
                        const float* __restrict__ m_WoutT,
                        const float* __restrict__ zb, const float* __restrict__ gW_outT,
                        const float* __restrict__ xt, const float* __restrict__ tok2,
                        const float* __restrict__ mu1, const float* __restrict__ rs1,
                        float* __restrict__ outpre, float* __restrict__ partials2){
  int ch = blockIdx.x & (SC_NC - 1), b = blockIdx.x >> 8;
  int l0 = ch * SC_T;
  int tok0 = b * LL + l0;
  int t = threadIdx.x;
  __shared__ float sB[SC_T * 16], sC[SC_T * 16];   // 2 KB
  __shared__ float sdtH[8 * 256];                  // 8 KB (half-tile staging)
  __shared__ float sxcH[8 * 256];                  // 8 KB
  __shared__ float szsH[8 * 256];                  // 8 KB
  __shared__ float yT[SC_T * 256];                 // 16 KB [l][d]
  __shared__ float sv[SC_T * 128];                 // 8 KB [tok][c]
  __shared__ float sS[1024], sQ[1024];             // 8 KB
  if (t < 256){
    sB[t] = Bmb[(size_t)tok0 * 16 + t];
    sC[t] = Cmb[(size_t)tok0 * 16 + t];
  }

  // scan phase: sq = t&3 (4 states), d = t>>2 (shfl-width-4 reduce)
  {
    int sq = t & 3, d = t >> 2;
    float4 Av = *(const float4*)&Aexp[d * 16 + sq * 4];   // pre-scaled by log2e
    float A0 = Av.x, A1 = Av.y, A2 = Av.z, A3 = Av.w;
    size_t cbase = ((size_t)(b * SC_NC + ch)) * 4096 + d * 16 + sq * 4;
    float4 hv = *(const float4*)&carryBuf[cbase];
    float h0 = hv.x, h1 = hv.y, h2 = hv.z, h3 = hv.w;
    float Dv = m_D[d];

    for (int half = 0; half < 2; ++half){
      __syncthreads();   // previous half's reads done (and sB/sC ready on first pass)
      // coalesced float4 staging of dt/xc/zs half-tiles (2048 floats each)
      size_t base = (size_t)(tok0 + half * 8) * 256;
      for (int u = t; u < 1536; u += 1024){
        int buf = u >> 9, idx = u & 511;
        const float* src = (buf == 0) ? (dtb + base) : (buf == 1) ? (xcb + base) : (zs + base);
        float* dst = (buf == 0) ? sdtH : (buf == 1) ? sxcH : szsH;
        ((float4*)dst)[idx] = ((const float4*)src)[idx];
      }
      __syncthreads();
      #pragma unroll
      for (int l2 = 0; l2 < 8; ++l2){
        int l = half * 8 + l2;
        float dt = sdtH[l2 * 256 + d];
        float xc = sxcH[l2 * 256 + d];
        float u = dt * xc;
        float4 bv = *(const float4*)&sB[l * 16 + sq * 4];
        float4 cv = *(const float4*)&sC[l * 16 + sq * 4];
        h0 = ex2_(dt * A0) * h0 + u * bv.x;
        h1 = ex2_(dt * A1) * h1 + u * bv.y;
        h2 = ex2_(dt * A2) * h2 + u * bv.z;
        h3 = ex2_(dt * A3) * h3 + u * bv.w;
        float p = h0 * cv.x + h1 * cv.y + h2 * cv.z + h3 * cv.w;
        p += __shfl_xor(p, 1, 4);
        p += __shfl_xor(p, 2, 4);
        if (sq == 0){
          float zv = szsH[l2 * 256 + d];
          yT[l * 256 + d] = (p + xc * Dv) * zv;
        }
      }
    }
  }
  __syncthreads();

  // mout GEMM: cc = t&127, th = t>>7 (0..7): toks th*2, th*2+1
  int cc = t & 127, th = t >> 7;
  float acc[2];
  acc[0] = acc[1] = 0.f;
  for (int dd = 0; dd < 256; ++dd){
    float w = m_WoutT[dd * 128 + cc];
    acc[0] += yT[(th * 2 + 0) * 256 + dd] * w;
    acc[1] += yT[(th * 2 + 1) * 256 + dd] * w;
  }
  #pragma unroll
  for (int j = 0; j < 2; ++j){
    int tok = th * 2 + j;
    float z = zb[(size_t)(tok0 + tok) * 128 + cc];
    sv[tok * 128 + cc] = acc[j] * z;
  }
  __syncthreads();

  float acc2[2];
  acc2[0] = acc2[1] = 0.f;
  for (int ci = 0; ci < 128; ++ci){
    float w = gW_outT[ci * 128 + cc];
    acc2[0] += sv[(th * 2 + 0) * 128 + ci] * w;
    acc2[1] += sv[(th * 2 + 1) * 128 + ci] * w;
  }
  float mu = mu1[b * 128 + cc], rsg = rs1[b * 128 + cc];
  float ps = 0.f, pq = 0.f;
  #pragma unroll
  for (int j = 0; j < 2; ++j){
    size_t idx = (size_t)(tok0 + th * 2 + j) * 128 + cc;
    float x = xt[idx];
    float xn = (x - mu) * rsg;
    xn = xn >= 0.f ? xn : 0.01f * xn;
    float v = xn + tok2[idx] + acc2[j];
    outpre[idx] = v;
    ps += v; pq += v * v;
  }
  sS[t] = ps; sQ[t] = pq;
  __syncthreads();
  if (t < 128){
    float S = 0.f, Q = 0.f;
    #pragma unroll
    for (int r = 0; r < 8; ++r){ S += sS[t + r * 128]; Q += sQ[t + r * 128]; }
    partials2[(size_t)blockIdx.x * 256 + t * 2]     = S;
    partials2[(size_t)blockIdx.x * 256 + t * 2 + 1] = Q;
  }
}

// ---------- final: instance-norm + NCHW transpose via LDS (grid 512) ----------
__global__ __launch_bounds__(256) void k_final(const float* __restrict__ outpre,
                        const float* __restrict__ mu,
                        const float* __restrict__ rs, float* __restrict__ out){
  int bid = blockIdx.x;            // b*256 + cg*128 + lg
  int lg = bid & 127, cg = (bid >> 7) & 1, b = bid >> 8;
  int t = threadIdx.x;
  __shared__ float sT[64 * 33];
  int l0 = lg * 32, c0 = cg * 64;
  #pragma unroll
  for (int k = 0; k < 8; ++k){
    int e = k * 256 + t;
    int l = e >> 6, cc = e & 63;
    float v = outpre[(size_t)(b * 4096 + l0 + l) * 128 + c0 + cc];
    v = (v - mu[b * 128 + c0 + cc]) * rs[b * 128 + c0 + cc];
    sT[cc * 33 + l] = v;
  }
  __syncthreads();
  #pragma unroll
  for (int k = 0; k < 8; ++k){
    int e = k * 256 + t;
    int cc = e >> 5, l = e & 31;
    out[((size_t)(b * 128 + c0 + cc)) * 4096 + l0 + l] = sT[cc * 33 + l];
  }
}

extern "C" void kernel_launch(void* const* d_in, const int* in_sizes, int n_in,
                              void* d_out, int out_size, void* d_ws, size_t ws_size,
                              hipStream_t stream){
  const float* inp    = (const float*)d_in[0];
  const float* skip   = (const float*)d_in[1];
  const float* w_up   = (const float*)d_in[2];
  const float* w_fuse = (const float*)d_in[3];
  const float* gW_in  = (const float*)d_in[4];
  const float* gW_gate= (const float*)d_in[5];
  const float* gb_gate= (const float*)d_in[6];
  const float* ln_g   = (const float*)d_in[7];
  const float* ln_b   = (const float*)d_in[8];
  const float* gW_out = (const float*)d_in[9];
  const float* m_Win  = (const float*)d_in[10];
  const float* m_convw= (const float*)d_in[11];
  const float* m_convb= (const float*)d_in[12];
  const float* m_Wx   = (const float*)d_in[13];
  const float* m_Wdt  = (const float*)d_in[14];
  const float* m_bdt  = (const float*)d_in[15];
  const float* m_Alog = (const float*)d_in[16];
  const float* m_D    = (const float*)d_in[17];
  const float* m_Wout = (const float*)d_in[18];
  float* out = (float*)d_out;

  float* ws = (float*)d_ws;
  float* W_eff    = ws;                        // 131072
  float* xt       = W_eff + 131072;            // 1048576
  float* tok2     = xt + 1048576;              // 1048576
  float* zb       = tok2 + 1048576;            // 1048576
  float* xmbuf    = zb + 1048576;              // 2097152 (xm, later outpre)
  float* zs       = xmbuf + 2097152;           // 2097152
  float* xcb      = zs + 2097152;              // 2097152
  float* dtb      = xcb + 2097152;             // 2097152
  float* Bmb      = dtb + 2097152;             // 131072
  float* Cmb      = Bmb + 131072;              // 131072
  float* chunkA   = Cmb + 131072;              // 2097152
  float* chunkH   = chunkA + 2097152;          // 2097152 (carry in place after B3)
  float* superA   = chunkH + 2097152;          // 131072
  float* superH   = superA + 131072;           // 131072 (supercarry after B2)
  float* partials = superH + 131072;           // 131072 (IN1, reused IN2)
  float* stats    = partials + 131072;         // 1024
  float* gW_inT   = stats + 1024;              // 16384
  float* gW_gateT = gW_inT + 16384;            // 16384
  float* gW_outT  = gW_gateT + 16384;          // 16384
  float* m_WinT   = gW_outT + 16384;           // 65536
  float* m_WoutT  = m_WinT + 65536;            // 32768
  float* AexpBuf  = m_WoutT + 32768;           // 4096

  float* mu1 = stats, *rs1 = stats + 256, *mu2 = stats + 512, *rs2 = stats + 768;
  float* xm = xmbuf;
  float* outpre = xmbuf;   // alias: xm dead after k_mid

  k_prep<<<1104, 256, 0, stream>>>(w_up, w_fuse, gW_in, gW_gate, gW_out, m_Win, m_Wout,
                                   m_Alog, W_eff, gW_inT, gW_gateT, gW_outT, m_WinT,
                                   m_WoutT, AexpBuf);

  k_fused<<<512, 512, 0, stream>>>(inp, skip, W_eff, w_fuse, xt, partials);
  k_stats2<<<2, 256, 0, stream>>>(partials, 256, 4096.f, mu1, rs1);

  k_front<<<1024, 512, 0, stream>>>(xt, mu1, rs1, gW_inT, gW_gateT, gb_gate, ln_g, ln_b,
                                    m_WinT, tok2, zb, xm, zs);
  k_mid<<<512, 1024, 0, stream>>>(xm, m_convw, m_convb, m_Wx, m_Wdt, m_bdt, AexpBuf,
                                  xcb, dtb, Bmb, Cmb, chunkA, chunkH);
  k_scanB1<<<512, 256, 0, stream>>>(chunkA, chunkH, superA, superH);
  k_scanB2<<<32, 256, 0, stream>>>(superA, superH);
  k_scanB3<<<512, 256, 0, stream>>>(chunkA, chunkH, superH);
  k_back<<<512, 1024, 0, stream>>>(dtb, xcb, Bmb, Cmb, AexpBuf, m_D, zs, chunkH,
                                   m_WoutT, zb, gW_outT, xt, tok2, mu1, rs1,
                                   outpre, partials);
  k_stats2<<<2, 256, 0, stream>>>(partials, 256, 4096.f, mu2, rs2);
  k_final<<<512, 256, 0, stream>>>(outpre, mu2, rs2, out);
}

// Round 15
// 207.821 us; speedup vs baseline: 1.5460x; 1.0277x over previous
//
#include <hip/hip_runtime.h>
#include <math.h>

#define BB 2
#define CIN 256
#define COUT 128
#define LL 4096
#define DI 256
#define DS 16

#define SC_T 16     // chunk length
#define SC_NC 256   // chunks per batch
#define SXP 260     // sxc pitch: bank step 4/row -> conflict-free
#define WXP 260     // sWx pitch
#define XNP 20      // xn/tn pitch in k_front (16B-aligned, 8-bank spread)
#define NSUP 16     // superchunks
#define CPS 16      // chunks per superchunk

#define L2E 1.44269504088896340736f
#define LN2 0.69314718055994530942f

// native transcendentals: v_exp_f32 (2^x), v_log_f32 (log2), v_rcp_f32
__device__ __forceinline__ float ex2_(float x){ return __builtin_amdgcn_exp2f(x); }
__device__ __forceinline__ float fexp_(float x){ return ex2_(x * L2E); }
__device__ __forceinline__ float rcp_(float x){ return __builtin_amdgcn_rcpf(x); }
__device__ __forceinline__ float silu_(float x){ return x * rcp_(1.f + fexp_(-x)); }
__device__ __forceinline__ float sigm_(float x){ return rcp_(1.f + fexp_(-x)); }
__device__ __forceinline__ float softplus_(float x){
  return (x > 20.f) ? x : LN2 * __builtin_amdgcn_logf(1.f + fexp_(x));
}

// ---------- prep: W_eff + all transposes + Aexp (one dispatch) ----------
__global__ __launch_bounds__(256) void k_prep(
    const float* __restrict__ w_up, const float* __restrict__ w_fuse,
    const float* __restrict__ gW_in, const float* __restrict__ gW_gate,
    const float* __restrict__ gW_out, const float* __restrict__ m_Win,
    const float* __restrict__ m_Wout, const float* __restrict__ m_Alog,
    float* __restrict__ W_eff,
    float* __restrict__ gW_inT, float* __restrict__ gW_gateT,
    float* __restrict__ gW_outT, float* __restrict__ m_WinT,
    float* __restrict__ m_WoutT, float* __restrict__ Aexp){
  int bid = blockIdx.x;
  if (bid < 512){
    int idx = bid * 256 + threadIdx.x;   // 4*256*128
    int o = idx & 127;
    int c = (idx >> 7) & 255;
    int p = idx >> 15;
    int kh = p >> 1, kw = p & 1;
    float acc = 0.f;
    #pragma unroll 8
    for (int i = 0; i < COUT; ++i)
      acc += w_up[((c * COUT + i) * 2 + kh) * 2 + kw] * w_fuse[i * COUT + o];
    W_eff[idx] = acc;
  } else {
    int idx = (bid - 512) * 256 + threadIdx.x;   // 151552 total
    if (idx < 16384){ int r = idx >> 7, c = idx & 127; gW_inT[c * 128 + r] = gW_in[idx]; }
    else if (idx < 32768){ int i = idx - 16384; int r = i >> 7, c = i & 127; gW_gateT[c * 128 + r] = gW_gate[i]; }
    else if (idx < 49152){ int i = idx - 32768; int r = i >> 7, c = i & 127; gW_outT[c * 128 + r] = gW_out[i]; }
    else if (idx < 114688){ int i = idx - 49152; int r = i >> 7, c = i & 127; m_WinT[c * 512 + r] = m_Win[i]; }
    else if (idx < 147456){ int i = idx - 114688; int r = i >> 8, c = i & 255; m_WoutT[c * 128 + r] = m_Wout[i]; }
    else if (idx < 151552){ int i = idx - 147456; Aexp[i] = -expf(m_Alog[i]) * L2E; }
  }
}

// ---------- fused tokens (16-px tile, grid 512, 512 thr) + partial stats ----------
__global__ __launch_bounds__(512, 8) void k_fused(const float* __restrict__ inp,
                        const float* __restrict__ skip,
                        const float* __restrict__ W_eff, const float* __restrict__ w_fuse,
                        float* __restrict__ fusedT, float* __restrict__ partials1){
  int bid = blockIdx.x;            // b*256 + h*4 + wt
  int wt = bid & 3;
  int h  = (bid >> 2) & 63;
  int b  = bid >> 8;
  int t  = threadIdx.x;            // 512
  int o  = t & 127;
  int g  = t >> 7;                 // 0..3 -> 4 pixels each

  __shared__ float sIn[256 * 8];
  __shared__ float sSk[128 * 16];
  __shared__ float sS[512], sQ[512];
  int hi = h >> 1;
  int wi0 = wt * 8;
  #pragma unroll
  for (int k = 0; k < 4; ++k){
    int e = k * 512 + t;
    int c = e >> 3, wl = e & 7;
    sIn[e] = inp[((b * 256 + c) * 32 + hi) * 32 + wi0 + wl];
  }
  #pragma unroll
  for (int k = 0; k < 4; ++k){
    int e = k * 512 + t;
    int i = e >> 4, wl2 = e & 15;
    sSk[e] = skip[((b * 128 + i) * 64 + h) * 64 + wt * 16 + wl2];
  }
  __syncthreads();

  float acc[4];
  #pragma unroll
  for (int j = 0; j < 4; ++j) acc[j] = 0.f;

  for (int par = 0; par < 2; ++par){
    int p = (h & 1) * 2 + par;
    const float* wptr = W_eff + (size_t)p * 256 * 128 + o;
    for (int c = 0; c < 256; ++c){
      float we = wptr[c * 128];
      acc[par]     += sIn[c * 8 + g * 2]     * we;
      acc[2 + par] += sIn[c * 8 + g * 2 + 1] * we;
    }
  }
  for (int i = 0; i < 128; ++i){
    float wf = w_fuse[(128 + i) * 128 + o];
    #pragma unroll
    for (int j = 0; j < 4; ++j)
      acc[j] += sSk[i * 16 + g * 4 + j] * wf;
  }
  float s4 = 0.f, q4 = 0.f;
  #pragma unroll
  for (int j = 0; j < 4; ++j){
    int w = wt * 16 + g * 4 + j;
    fusedT[((size_t)(b * 4096 + h * 64 + w)) * 128 + o] = acc[j];
    s4 += acc[j]; q4 += acc[j] * acc[j];
  }
  sS[t] = s4; sQ[t] = q4;
  __syncthreads();
  if (t < 128){
    partials1[(size_t)bid * 256 + t * 2]     = sS[t] + sS[t + 128] + sS[t + 256] + sS[t + 384];
    partials1[(size_t)bid * 256 + t * 2 + 1] = sQ[t] + sQ[t + 128] + sQ[t + 256] + sQ[t + 384];
  }
}

// ---------- reduce partials -> mu, rs ----------
__global__ __launch_bounds__(256) void k_stats2(const float* __restrict__ partials, int nb,
                         float cnt, float* __restrict__ mu, float* __restrict__ rs){
  int b = blockIdx.x;
  int t = threadIdx.x;
  int c = t & 127, half = t >> 7;
  int n2 = nb >> 1;
  float S = 0.f, Q = 0.f;
  for (int k = half * n2; k < (half + 1) * n2; ++k){
    S += partials[(size_t)(b * nb + k) * 256 + c * 2];
    Q += partials[(size_t)(b * nb + k) * 256 + c * 2 + 1];
  }
  __shared__ float sS[256], sQ[256];
  sS[t] = S; sQ[t] = Q;
  __syncthreads();
  if (t < 128){
    float Sa = sS[t] + sS[t + 128], Qa = sQ[t] + sQ[t + 128];
    float m = Sa / cnt;
    mu[b * 128 + t] = m;
    rs[b * 128 + t] = rsqrtf(Qa / cnt - m * m + 1e-5f);
  }
}

// ---------- front: 16-token tile (grid 512, 512 thr): norm+leaky -> (tok2,z) -> LN -> xz GEMM ----------
__global__ __launch_bounds__(512, 4) void k_front(const float* __restrict__ xt,
                      const float* __restrict__ mu1, const float* __restrict__ rs1,
                      const float* __restrict__ gW_inT, const float* __restrict__ gW_gateT,
                      const float* __restrict__ gb_gate,
                      const float* __restrict__ ln_g, const float* __restrict__ ln_b,
                      const float* __restrict__ m_WinT,
                      float* __restrict__ tok2, float* __restrict__ zb,
                      float* __restrict__ xm, float* __restrict__ zs){
  int tok0 = blockIdx.x * 16;
  int b = tok0 >> 12;
  int t = threadIdx.x;
  __shared__ float xn[128 * XNP];   // [c][tok], pitch 20
  __shared__ float tn[128 * XNP];
  __shared__ float aT[16 * 132];    // [tok][o]
  __shared__ float sMu[16], sRs[16];

  // stage + IN1-norm + leaky (coalesced global; 8-way LDS write conflicts tolerated)
  #pragma unroll
  for (int k = 0; k < 4; ++k){
    int e = k * 512 + t;
    int tok = e >> 7, c = e & 127;
    float v = xt[(size_t)(tok0 + tok) * 128 + c];
    v = (v - mu1[b * 128 + c]) * rs1[b * 128 + c];
    v = v >= 0.f ? v : 0.01f * v;
    xn[c * XNP + tok] = v;
  }
  __syncthreads();

  // GEMM1: o = t&127, th = t>>7 (0..3): toks th*4..th*4+3
  int o = t & 127, th = t >> 7;
  float accA[4], accG[4];
  #pragma unroll
  for (int j = 0; j < 4; ++j){ accA[j] = 0.f; accG[j] = 0.f; }
  for (int c = 0; c < 128; ++c){
    float wa = gW_inT[c * 128 + o];
    float wg = gW_gateT[c * 128 + o];
    float4 x = *(const float4*)&xn[c * XNP + th * 4];   // 16B-aligned broadcast
    accA[0] += x.x * wa; accA[1] += x.y * wa; accA[2] += x.z * wa; accA[3] += x.w * wa;
    accG[0] += x.x * wg; accG[1] += x.y * wg; accG[2] += x.z * wg; accG[3] += x.w * wg;
  }
  float gb = gb_gate[o];
  #pragma unroll
  for (int j = 0; j < 4; ++j){
    int tok = th * 4 + j;
    tok2[(size_t)(tok0 + tok) * 128 + o] = accA[j];
    zb[(size_t)(tok0 + tok) * 128 + o] = sigm_(silu_(accG[j] + gb));
    aT[tok * 132 + o] = accA[j];
  }
  __syncthreads();

  // LN stats: 256 threads = 16 toks x 16 lanes
  if (t < 256){
    int tok = t >> 4, i = t & 15;
    float s = 0.f, q = 0.f;
    #pragma unroll
    for (int j = 0; j < 8; ++j){ float a = aT[tok * 132 + i * 8 + j]; s += a; q += a * a; }
    s += __shfl_down(s, 8, 16); q += __shfl_down(q, 8, 16);
    s += __shfl_down(s, 4, 16); q += __shfl_down(q, 4, 16);
    s += __shfl_down(s, 2, 16); q += __shfl_down(q, 2, 16);
    s += __shfl_down(s, 1, 16); q += __shfl_down(q, 1, 16);
    if (i == 0){
      float m = s / 128.f;
      sMu[tok] = m;
      sRs[tok] = rsqrtf(q / 128.f - m * m + 1e-5f);
    }
  }
  __syncthreads();
  // tn = LN(aT): e-mapping (c = e>>4, tok = e&15) keeps LDS writes spread
  #pragma unroll
  for (int k = 0; k < 4; ++k){
    int e = k * 512 + t;
    int c = e >> 4, tok = e & 15;
    tn[c * XNP + tok] = (aT[tok * 132 + c] - sMu[tok]) * sRs[tok] * ln_g[c] + ln_b[c];
  }
  __syncthreads();

  // GEMM2: thread = output column n = t (0..511), 16 toks
  float a0[16];
  #pragma unroll
  for (int j = 0; j < 16; ++j) a0[j] = 0.f;
  for (int c = 0; c < 128; ++c){
    float w = m_WinT[c * 512 + t];
    const float4* xp = (const float4*)&tn[c * XNP];
    float4 x0 = xp[0], x1 = xp[1], x2 = xp[2], x3 = xp[3];
    a0[0]  += x0.x * w; a0[1]  += x0.y * w; a0[2]  += x0.z * w; a0[3]  += x0.w * w;
    a0[4]  += x1.x * w; a0[5]  += x1.y * w; a0[6]  += x1.z * w; a0[7]  += x1.w * w;
    a0[8]  += x2.x * w; a0[9]  += x2.y * w; a0[10] += x2.z * w; a0[11] += x2.w * w;
    a0[12] += x3.x * w; a0[13] += x3.y * w; a0[14] += x3.z * w; a0[15] += x3.w * w;
  }
  if (t < 256){
    #pragma unroll
    for (int j = 0; j < 16; ++j)
      xm[(size_t)(tok0 + j) * 256 + t] = a0[j];
  } else {
    #pragma unroll
    for (int j = 0; j < 16; ++j)
      zs[(size_t)(tok0 + j) * 256 + (t - 256)] = silu_(a0[j]);
  }
}

// ---------- mid: conv -> x_dbl(LDS weights) -> dt(once) -> local scan  (1024 thr, grid 512) ----------
__global__ __launch_bounds__(1024, 2) void k_mid(const float* __restrict__ xm,
                    const float* __restrict__ cw, const float* __restrict__ cb,
                    const float* __restrict__ m_Wx, const float* __restrict__ m_Wdt,
                    const float* __restrict__ m_bdt, const float* __restrict__ Aexp,
                    float* __restrict__ xcb, float* __restrict__ dtb,
                    float* __restrict__ Bmb, float* __restrict__ Cmb,
                    float* __restrict__ chunkA, float* __restrict__ chunkH){
  int ch = blockIdx.x & (SC_NC - 1), b = blockIdx.x >> 8;
  int l0 = ch * SC_T;
  int tok0 = b * LL + l0;
  int t = threadIdx.x;
  __shared__ float sWx[40 * WXP];     // 41.6 KB
  __shared__ float sxc[SC_T * SXP];   // 16.6 KB
  __shared__ float sdt[SC_T * 256];   // 16 KB
  __shared__ float sdbl[SC_T * 40];   // 2.5 KB

  #pragma unroll
  for (int u = 0; u < 10; ++u){
    int e = u * 1024 + t;
    int j = e >> 8, k = e & 255;
    sWx[j * WXP + k] = m_Wx[e];
  }

  {
    int d = t & 255, q = t >> 8;
    float xr[7];
    #pragma unroll
    for (int r = 0; r < 7; ++r){
      int l = l0 + q * 4 - 3 + r;
      xr[r] = (l >= 0) ? xm[(size_t)(b * LL + l) * 256 + d] : 0.f;
    }
    float4 cwv = *(const float4*)&cw[d * 4];
    float cbv = cb[d];
    #pragma unroll
    for (int j = 0; j < 4; ++j){
      float a = cbv + xr[j] * cwv.x + xr[j + 1] * cwv.y + xr[j + 2] * cwv.z + xr[j + 3] * cwv.w;
      a = silu_(a);
      sxc[(q * 4 + j) * SXP + d] = a;
    }
  }
  __syncthreads();

  {
    int tok = t >> 6, d0 = (t & 63) * 4;
    *(float4*)&xcb[(size_t)(tok0 + tok) * 256 + d0] = *(const float4*)&sxc[tok * SXP + d0];
  }

  if (t < 640){
    int i, tok;
    if (t < 512){ i = 8 + (t & 31); tok = t >> 5; }
    else        { int u = t - 512; i = u & 7; tok = u >> 3; }
    const float4* wr = (const float4*)&sWx[i * WXP];
    const float4* xr = (const float4*)&sxc[tok * SXP];
    float ac[4];
    #pragma unroll
    for (int c4 = 0; c4 < 4; ++c4){
      float s0 = 0.f, s1 = 0.f, s2 = 0.f, s3 = 0.f;
      #pragma unroll
      for (int k4 = 0; k4 < 16; ++k4){
        float4 w = wr[c4 * 16 + k4];
        float4 x = xr[c4 * 16 + k4];
        s0 += x.x * w.x; s1 += x.y * w.y; s2 += x.z * w.z; s3 += x.w * w.w;
      }
      ac[c4] = (s0 + s1) + (s2 + s3);
    }
    float a = (ac[0] + ac[1]) + (ac[2] + ac[3]);
    sdbl[tok * 40 + i] = a;
    if (t < 512){
      int ii = i - 8;
      if (ii < 16) Bmb[(size_t)(tok0 + tok) * 16 + ii] = a;
      else         Cmb[(size_t)(tok0 + tok) * 16 + (ii - 16)] = a;
    }
  }
  __syncthreads();

  {
    int d = t & 255;
    float4 wd0 = *(const float4*)&m_Wdt[d * 8];
    float4 wd1 = *(const float4*)&m_Wdt[d * 8 + 4];
    float bdt = m_bdt[d];
    int tq = t >> 8;
    #pragma unroll
    for (int k = 0; k < 4; ++k){
      int tok = k * 4 + tq;
      const float4* dp = (const float4*)&sdbl[tok * 40];
      float4 d0 = dp[0], d1 = dp[1];
      float dtr = bdt + d0.x * wd0.x + d0.y * wd0.y + d0.z * wd0.z + d0.w * wd0.w
                      + d1.x * wd1.x + d1.y * wd1.y + d1.z * wd1.z + d1.w * wd1.w;
      sdt[tok * 256 + d] = softplus_(dtr);
    }
  }
  __syncthreads();

  {
    int tok = t >> 6, d0 = (t & 63) * 4;
    *(float4*)&dtb[(size_t)(tok0 + tok) * 256 + d0] = *(const float4*)&sdt[tok * 256 + d0];
  }

  {
    int d = t & 255, sq = t >> 8;
    float4 Av = *(const float4*)&Aexp[d * 16 + sq * 4];   // pre-scaled by log2e
    float A0 = Av.x, A1 = Av.y, A2 = Av.z, A3 = Av.w;
    float h0 = 0.f, h1 = 0.f, h2 = 0.f, h3 = 0.f;
    float sumdt = 0.f;
    #pragma unroll 4
    for (int j = 0; j < SC_T; ++j){
      float dt = sdt[j * 256 + d];
      sumdt += dt;
      float u = dt * sxc[j * SXP + d];
      float4 bv = *(const float4*)&sdbl[j * 40 + 8 + sq * 4];
      h0 = ex2_(dt * A0) * h0 + u * bv.x;
      h1 = ex2_(dt * A1) * h1 + u * bv.y;
      h2 = ex2_(dt * A2) * h2 + u * bv.z;
      h3 = ex2_(dt * A3) * h3 + u * bv.w;
    }
    size_t base = ((size_t)(b * SC_NC + ch)) * 4096 + d * 16 + sq * 4;
    float4 va, vh;
    va.x = ex2_(A0 * sumdt); va.y = ex2_(A1 * sumdt);
    va.z = ex2_(A2 * sumdt); va.w = ex2_(A3 * sumdt);
    vh.x = h0; vh.y = h1; vh.z = h2; vh.w = h3;
    *(float4*)&chunkA[base] = va;
    *(float4*)&chunkH[base] = vh;
  }
}

// ---------- scanB1: super-summaries over CPS chunks ----------
__global__ __launch_bounds__(256) void k_scanB1(const float* __restrict__ chunkA,
                        const float* __restrict__ chunkH,
                        float* __restrict__ superA, float* __restrict__ superH){
  int blk = blockIdx.x;                 // 2 * NSUP * 16
  int ds = (blk & 15) * 256 + threadIdx.x;
  int sc = (blk >> 4) & (NSUP - 1);
  int b  = blk >> 8;
  float sA = 1.f, sH = 0.f;
  for (int j = 0; j < CPS; ++j){
    size_t idx = ((size_t)(b * SC_NC + sc * CPS + j)) * 4096 + ds;
    float A = chunkA[idx], H = chunkH[idx];
    sA = A * sA;
    sH = A * sH + H;
  }
  size_t o = ((size_t)(b * NSUP + sc)) * 4096 + ds;
  superA[o] = sA; superH[o] = sH;
}

// ---------- scanB2: serial combine over supers; supercarry in place ----------
__global__ __launch_bounds__(256) void k_scanB2(const float* __restrict__ superA,
                        float* __restrict__ superH){
  int gid = blockIdx.x * 256 + threadIdx.x;  // 8192
  int ds = gid & 4095;
  int b = gid >> 12;
  float carry = 0.f;
  #pragma unroll
  for (int sc = 0; sc < NSUP; ++sc){
    size_t idx = ((size_t)(b * NSUP + sc)) * 4096 + ds;
    float A = superA[idx], H = superH[idx];
    superH[idx] = carry;
    carry = A * carry + H;
  }
}

// ---------- scanB3: walk chunks with supercarry; carry in place into chunkH ----------
__global__ __launch_bounds__(256) void k_scanB3(const float* __restrict__ chunkA,
                        float* __restrict__ chunkH, const float* __restrict__ superH){
  int blk = blockIdx.x;
  int ds = (blk & 15) * 256 + threadIdx.x;
  int sc = (blk >> 4) & (NSUP - 1);
  int b  = blk >> 8;
  float carry = superH[((size_t)(b * NSUP + sc)) * 4096 + ds];
  for (int j = 0; j < CPS; ++j){
    size_t idx = ((size_t)(b * SC_NC + sc * CPS + j)) * 4096 + ds;
    float A = chunkA[idx], H = chunkH[idx];
    chunkH[idx] = carry;
    carry = A * carry + H;
  }
}

// ---------- back: LDS-staged re-scan + mout -> gate -> out proj -> residual + IN2 ----------
__global__ __launch_bounds__(1024, 8) void k_back(const float* __restrict__ dtb,
                        const float* __restrict__ xcb,
                        const float* __restrict__ Bmb, const float* __restrict__ Cmb,
                        const float* __restrict__ Aexp, const float* __restrict__ m_D,
                        const float* __restrict__ zs, const float* __restrict__ carryBuf,
                        const float* __restrict__ m_WoutT,
                        const float* __restrict__ zb, const float* __restrict__ gW_outT,
                        const float* __restrict__ xt, const float* __restrict__ tok2,
                        const float* __restrict__ mu1, const float* __restrict__ rs1,
                        float* __restrict__ outpre, float* __restrict__ partials2){
  int ch = blockIdx.x & (SC_NC - 1), b = blockIdx.x >> 8;
  int l0 = ch * SC_T;
  int tok0 = b * LL + l0;
  int t = threadIdx.x;
  __shared__ float sB[SC_T * 16], sC[SC_T * 16];   // 2 KB
  __shared__ float sdtH[8 * 256];                  // 8 KB (half-tile staging)
  __shared__ float sxcH[8 * 256];                  // 8 KB
  __shared__ float szsH[8 * 256];                  // 8 KB
  __shared__ float yT[SC_T * 256];                 // 16 KB [l][d]
  __shared__ float sv[SC_T * 128];                 // 8 KB [tok][c]
  __shared__ float sS[1024], sQ[1024];             // 8 KB
  if (t < 256){
    sB[t] = Bmb[(size_t)tok0 * 16 + t];
    sC[t] = Cmb[(size_t)tok0 * 16 + t];
  }

  // scan phase: sq = t&3 (4 states), d = t>>2 (shfl-width-4 reduce)
  {
    int sq = t & 3, d = t >> 2;
    float4 Av = *(const float4*)&Aexp[d * 16 + sq * 4];   // pre-scaled by log2e
    float A0 = Av.x, A1 = Av.y, A2 = Av.z, A3 = Av.w;
    size_t cbase = ((size_t)(b * SC_NC + ch)) * 4096 + d * 16 + sq * 4;
    float4 hv = *(const float4*)&carryBuf[cbase];
    float h0 = hv.x, h1 = hv.y, h2 = hv.z, h3 = hv.w;
    float Dv = m_D[d];

    for (int half = 0; half < 2; ++half){
      __syncthreads();   // previous half's reads done (and sB/sC ready on first pass)
      // coalesced float4 staging of dt/xc/zs half-tiles (2048 floats each)
      size_t base = (size_t)(tok0 + half * 8) * 256;
      for (int u = t; u < 1536; u += 1024){
        int buf = u >> 9, idx = u & 511;
        const float* src = (buf == 0) ? (dtb + base) : (buf == 1) ? (xcb + base) : (zs + base);
        float* dst = (buf == 0) ? sdtH : (buf == 1) ? sxcH : szsH;
        ((float4*)dst)[idx] = ((const float4*)src)[idx];
      }
      __syncthreads();
      #pragma unroll
      for (int l2 = 0; l2 < 8; ++l2){
        int l = half * 8 + l2;
        float dt = sdtH[l2 * 256 + d];
        float xc = sxcH[l2 * 256 + d];
        float u = dt * xc;
        float4 bv = *(const float4*)&sB[l * 16 + sq * 4];
        float4 cv = *(const float4*)&sC[l * 16 + sq * 4];
        h0 = ex2_(dt * A0) * h0 + u * bv.x;
        h1 = ex2_(dt * A1) * h1 + u * bv.y;
        h2 = ex2_(dt * A2) * h2 + u * bv.z;
        h3 = ex2_(dt * A3) * h3 + u * bv.w;
        float p = h0 * cv.x + h1 * cv.y + h2 * cv.z + h3 * cv.w;
        p += __shfl_xor(p, 1, 4);
        p += __shfl_xor(p, 2, 4);
        if (sq == 0){
          float zv = szsH[l2 * 256 + d];
          yT[l * 256 + d] = (p + xc * Dv) * zv;
        }
      }
    }
  }
  __syncthreads();

  // mout GEMM: cc = t&127, th = t>>7 (0..7): toks th*2, th*2+1
  int cc = t & 127, th = t >> 7;
  float acc[2];
  acc[0] = acc[1] = 0.f;
  for (int dd = 0; dd < 256; ++dd){
    float w = m_WoutT[dd * 128 + cc];
    acc[0] += yT[(th * 2 + 0) * 256 + dd] * w;
    acc[1] += yT[(th * 2 + 1) * 256 + dd] * w;
  }
  #pragma unroll
  for (int j = 0; j < 2; ++j){
    int tok = th * 2 + j;
    float z = zb[(size_t)(tok0 + tok) * 128 + cc];
    sv[tok * 128 + cc] = acc[j] * z;
  }
  __syncthreads();

  float acc2[2];
  acc2[0] = acc2[1] = 0.f;
  for (int ci = 0; ci < 128; ++ci){
    float w = gW_outT[ci * 128 + cc];
    acc2[0] += sv[(th * 2 + 0) * 128 + ci] * w;
    acc2[1] += sv[(th * 2 + 1) * 128 + ci] * w;
  }
  float mu = mu1[b * 128 + cc], rsg = rs1[b * 128 + cc];
  float ps = 0.f, pq = 0.f;
  #pragma unroll
  for (int j = 0; j < 2; ++j){
    size_t idx = (size_t)(tok0 + th * 2 + j) * 128 + cc;
    float x = xt[idx];
    float xn = (x - mu) * rsg;
    xn = xn >= 0.f ? xn : 0.01f * xn;
    float v = xn + tok2[idx] + acc2[j];
    outpre[idx] = v;
    ps += v; pq += v * v;
  }
  sS[t] = ps; sQ[t] = pq;
  __syncthreads();
  if (t < 128){
    float S = 0.f, Q = 0.f;
    #pragma unroll
    for (int r = 0; r < 8; ++r){ S += sS[t + r * 128]; Q += sQ[t + r * 128]; }
    partials2[(size_t)blockIdx.x * 256 + t * 2]     = S;
    partials2[(size_t)blockIdx.x * 256 + t * 2 + 1] = Q;
  }
}

// ---------- final: instance-norm + NCHW transpose via LDS (grid 512) ----------
__global__ __launch_bounds__(256) void k_final(const float* __restrict__ outpre,
                        const float* __restrict__ mu,
                        const float* __restrict__ rs, float* __restrict__ out){
  int bid = blockIdx.x;            // b*256 + cg*128 + lg
  int lg = bid & 127, cg = (bid >> 7) & 1, b = bid >> 8;
  int t = threadIdx.x;
  __shared__ float sT[64 * 33];
  int l0 = lg * 32, c0 = cg * 64;
  #pragma unroll
  for (int k = 0; k < 8; ++k){
    int e = k * 256 + t;
    int l = e >> 6, cc = e & 63;
    float v = outpre[(size_t)(b * 4096 + l0 + l) * 128 + c0 + cc];
    v = (v - mu[b * 128 + c0 + cc]) * rs[b * 128 + c0 + cc];
    sT[cc * 33 + l] = v;
  }
  __syncthreads();
  #pragma unroll
  for (int k = 0; k < 8; ++k){
    int e = k * 256 + t;
    int cc = e >> 5, l = e & 31;
    out[((size_t)(b * 128 + c0 + cc)) * 4096 + l0 + l] = sT[cc * 33 + l];
  }
}

extern "C" void kernel_launch(void* const* d_in, const int* in_sizes, int n_in,
                              void* d_out, int out_size, void* d_ws, size_t ws_size,
                              hipStream_t stream){
  const float* inp    = (const float*)d_in[0];
  const float* skip   = (const float*)d_in[1];
  const float* w_up   = (const float*)d_in[2];
  const float* w_fuse = (const float*)d_in[3];
  const float* gW_in  = (const float*)d_in[4];
  const float* gW_gate= (const float*)d_in[5];
  const float* gb_gate= (const float*)d_in[6];
  const float* ln_g   = (const float*)d_in[7];
  const float* ln_b   = (const float*)d_in[8];
  const float* gW_out = (const float*)d_in[9];
  const float* m_Win  = (const float*)d_in[10];
  const float* m_convw= (const float*)d_in[11];
  const float* m_convb= (const float*)d_in[12];
  const float* m_Wx   = (const float*)d_in[13];
  const float* m_Wdt  = (const float*)d_in[14];
  const float* m_bdt  = (const float*)d_in[15];
  const float* m_Alog = (const float*)d_in[16];
  const float* m_D    = (const float*)d_in[17];
  const float* m_Wout = (const float*)d_in[18];
  float* out = (float*)d_out;

  float* ws = (float*)d_ws;
  float* W_eff    = ws;                        // 131072
  float* xt       = W_eff + 131072;            // 1048576
  float* tok2     = xt + 1048576;              // 1048576
  float* zb       = tok2 + 1048576;            // 1048576
  float* xmbuf    = zb + 1048576;              // 2097152 (xm, later outpre)
  float* zs       = xmbuf + 2097152;           // 2097152
  float* xcb      = zs + 2097152;              // 2097152
  float* dtb      = xcb + 2097152;             // 2097152
  float* Bmb      = dtb + 2097152;             // 131072
  float* Cmb      = Bmb + 131072;              // 131072
  float* chunkA   = Cmb + 131072;              // 2097152
  float* chunkH   = chunkA + 2097152;          // 2097152 (carry in place after B3)
  float* superA   = chunkH + 2097152;          // 131072
  float* superH   = superA + 131072;           // 131072 (supercarry after B2)
  float* partials = superH + 131072;           // 131072 (IN1, reused IN2)
  float* stats    = partials + 131072;         // 1024
  float* gW_inT   = stats + 1024;              // 16384
  float* gW_gateT = gW_inT + 16384;            // 16384
  float* gW_outT  = gW_gateT + 16384;          // 16384
  float* m_WinT   = gW_outT + 16384;           // 65536
  float* m_WoutT  = m_WinT + 65536;            // 32768
  float* AexpBuf  = m_WoutT + 32768;           // 4096

  float* mu1 = stats, *rs1 = stats + 256, *mu2 = stats + 512, *rs2 = stats + 768;
  float* xm = xmbuf;
  float* outpre = xmbuf;   // alias: xm dead after k_mid

  k_prep<<<1104, 256, 0, stream>>>(w_up, w_fuse, gW_in, gW_gate, gW_out, m_Win, m_Wout,
                                   m_Alog, W_eff, gW_inT, gW_gateT, gW_outT, m_WinT,
                                   m_WoutT, AexpBuf);

  k_fused<<<512, 512, 0, stream>>>(inp, skip, W_eff, w_fuse, xt, partials);
  k_stats2<<<2, 256, 0, stream>>>(partials, 256, 4096.f, mu1, rs1);

  k_front<<<512, 512, 0, stream>>>(xt, mu1, rs1, gW_inT, gW_gateT, gb_gate, ln_g, ln_b,
                                   m_WinT, tok2, zb, xm, zs);
  k_mid<<<512, 1024, 0, stream>>>(xm, m_convw, m_convb, m_Wx, m_Wdt, m_bdt, AexpBuf,
                                  xcb, dtb, Bmb, Cmb, chunkA, chunkH);
  k_scanB1<<<512, 256, 0, stream>>>(chunkA, chunkH, superA, superH);
  k_scanB2<<<32, 256, 0, stream>>>(superA, superH);
  k_scanB3<<<512, 256, 0, stream>>>(chunkA, chunkH, superH);
  k_back<<<512, 1024, 0, stream>>>(dtb, xcb, Bmb, Cmb, AexpBuf, m_D, zs, chunkH,
                                   m_WoutT, zb, gW_outT, xt, tok2, mu1, rs1,
                                   outpre, partials);
  k_stats2<<<2, 256, 0, stream>>>(partials, 256, 4096.f, mu2, rs2);
  k_final<<<512, 256, 0, stream>>>(outpre, mu2, rs2, out);
}